// Round 2
// baseline (7158.405 us; speedup 1.0000x reference)
//
#include <hip/hip_runtime.h>
#include <hip/hip_bf16.h>

typedef __bf16 bf8_t __attribute__((ext_vector_type(8)));
typedef __bf16 bf4_t __attribute__((ext_vector_type(4)));
typedef float  f32x4 __attribute__((ext_vector_type(4)));

constexpr int N_NODES = 100000;
constexpr int E_ORIG  = 600000;
constexpr int E_LINE  = 1200000;

static inline int cdiv(int a, int b) { return (a + b - 1) / b; }

// ---- scatter add, f32 source: Q[dst] += X[src]  (Q pre-initialized with x) ----
__global__ void k_scatter_f32(const float* __restrict__ X, float* __restrict__ Q,
                              const int* __restrict__ src, const int* __restrict__ dst, int E) {
    int gid = blockIdx.x * 256 + threadIdx.x;
    int e = gid >> 5;
    if (e >= E) return;
    int c = gid & 31;
    int s = src[e], d = dst[e];
    float4 v = ((const float4*)(X + (size_t)s * 128))[c];
    float* q = Q + (size_t)d * 128 + (size_t)c * 4;
    unsafeAtomicAdd(q + 0, v.x);
    unsafeAtomicAdd(q + 1, v.y);
    unsafeAtomicAdd(q + 2, v.z);
    unsafeAtomicAdd(q + 3, v.w);
}

// ---- scatter add, bf16 source into f32 target ----
__global__ void k_scatter_b16(const __bf16* __restrict__ X, float* __restrict__ Q,
                              const int* __restrict__ src, const int* __restrict__ dst, int E) {
    int gid = blockIdx.x * 256 + threadIdx.x;
    int e = gid >> 5;
    if (e >= E) return;
    int c = gid & 31;
    int s = src[e], d = dst[e];
    bf4_t v = *(const bf4_t*)(X + (size_t)s * 128 + (size_t)c * 4);
    float* q = Q + (size_t)d * 128 + (size_t)c * 4;
    unsafeAtomicAdd(q + 0, (float)v[0]);
    unsafeAtomicAdd(q + 1, (float)v[1]);
    unsafeAtomicAdd(q + 2, (float)v[2]);
    unsafeAtomicAdd(q + 3, (float)v[3]);
}

// ---- bf16 -> f32 expand (initializes AGG = x before scatter) ----
__global__ void k_b2f(const __bf16* __restrict__ X, float* __restrict__ Q, int n8) {
    int i = blockIdx.x * 256 + threadIdx.x;
    if (i >= n8) return;
    bf8_t v = ((const bf8_t*)X)[i];
    float4 a = {(float)v[0], (float)v[1], (float)v[2], (float)v[3]};
    float4 b = {(float)v[4], (float)v[5], (float)v[6], (float)v[7]};
    ((float4*)Q)[2 * i]     = a;
    ((float4*)Q)[2 * i + 1] = b;
}

// ---- h[e] = Y[p0[e]] + Y[p1[e]]  (f32 in, bf16 out) ----
__global__ void k_pair_gather(const float* __restrict__ Y, const int* __restrict__ pairs,
                              __bf16* __restrict__ H, int E) {
    int gid = blockIdx.x * 256 + threadIdx.x;
    int e = gid >> 4;
    if (e >= E) return;
    int c = gid & 15;
    int p0 = pairs[2 * e], p1 = pairs[2 * e + 1];
    const float* y0 = Y + (size_t)p0 * 128 + c * 8;
    const float* y1 = Y + (size_t)p1 * 128 + c * 8;
    float4 a0 = *(const float4*)y0, a1 = *(const float4*)(y0 + 4);
    float4 b0 = *(const float4*)y1, b1 = *(const float4*)(y1 + 4);
    bf8_t o;
    o[0] = (__bf16)(a0.x + b0.x); o[1] = (__bf16)(a0.y + b0.y);
    o[2] = (__bf16)(a0.z + b0.z); o[3] = (__bf16)(a0.w + b0.w);
    o[4] = (__bf16)(a1.x + b1.x); o[5] = (__bf16)(a1.y + b1.y);
    o[6] = (__bf16)(a1.z + b1.z); o[7] = (__bf16)(a1.w + b1.w);
    *(bf8_t*)(H + (size_t)e * 128 + c * 8) = o;
}

// ---- fused GEMM: out = act(bn(A @ W + b)) ; A is [M,128] (f32 or bf16), W f32 [128,NC] ----
template<int NC, bool AF32, bool BN, bool RELU, bool OUTF32>
__launch_bounds__(256, 2)
__global__ void k_gemm(const void* __restrict__ Ap, int M,
                       const float* __restrict__ W,
                       const float* __restrict__ bias,
                       const float* __restrict__ bg, const float* __restrict__ bb,
                       const float* __restrict__ bm, const float* __restrict__ bv,
                       void* __restrict__ outp) {
    constexpr int NT = NC / 16;
    __shared__ __bf16 sW[128 * NC];
    __shared__ float sS[NC];
    __shared__ float sT[NC];

    // stage W into LDS, bf16, B-fragment-major:
    // frag(c,s): lane l, elem j  <- W[k = s*32 + (l>>4)*8 + j][n = c*16 + (l&15)]
    const float4* W4 = (const float4*)W;
    for (int e = threadIdx.x; e < 32 * NC; e += 256) {
        float4 w = W4[e];
        unsigned flat = (unsigned)e * 4;
        unsigned k = flat / NC, n = flat % NC;     // 4 consecutive n share k and c
        unsigned c = n >> 4, s = k >> 5, hi = (k >> 3) & 3, j = k & 7;
        unsigned l0 = (hi << 4) | (n & 15);
        unsigned base = ((c * 4 + s) * 64 + l0) * 8 + j;
        sW[base]      = (__bf16)w.x;
        sW[base + 8]  = (__bf16)w.y;
        sW[base + 16] = (__bf16)w.z;
        sW[base + 24] = (__bf16)w.w;
    }
    // fold BN + bias into per-column scale/shift: out = dot*S + T
    for (int n = threadIdx.x; n < NC; n += 256) {
        float b = bias[n];
        float S = 1.0f, T = b;
        if (BN) {
            float g = bg[n], be = bb[n], m = bm[n], v = bv[n];
            S = g * rsqrtf(v + 1e-5f);
            T = b * S + (be - m * S);
        }
        sS[n] = S; sT[n] = T;
    }
    __syncthreads();

    const int lane = threadIdx.x & 63;
    const int wv   = threadIdx.x >> 6;
    const int rowBase = blockIdx.x * 256 + wv * 64;
    const int m0 = lane & 15, kq = lane >> 4;

    f32x4 acc[4][NT];
    #pragma unroll
    for (int rt = 0; rt < 4; ++rt)
        #pragma unroll
        for (int ct = 0; ct < NT; ++ct)
            acc[rt][ct] = (f32x4){0.f, 0.f, 0.f, 0.f};

    #pragma unroll
    for (int s = 0; s < 4; ++s) {
        bf8_t fa[4];
        #pragma unroll
        for (int rt = 0; rt < 4; ++rt) {
            int r = rowBase + rt * 16 + m0;
            r = r < M ? r : M - 1;                 // clamp; tail rows never stored
            if constexpr (AF32) {
                const float* ap = (const float*)Ap + (size_t)r * 128 + s * 32 + kq * 8;
                float4 x0 = *(const float4*)ap;
                float4 x1 = *(const float4*)(ap + 4);
                bf8_t f;
                f[0] = (__bf16)x0.x; f[1] = (__bf16)x0.y; f[2] = (__bf16)x0.z; f[3] = (__bf16)x0.w;
                f[4] = (__bf16)x1.x; f[5] = (__bf16)x1.y; f[6] = (__bf16)x1.z; f[7] = (__bf16)x1.w;
                fa[rt] = f;
            } else {
                fa[rt] = *(const bf8_t*)((const __bf16*)Ap + (size_t)r * 128 + s * 32 + kq * 8);
            }
        }
        #pragma unroll
        for (int ct = 0; ct < NT; ++ct) {
            bf8_t fw = *(const bf8_t*)&sW[((ct * 4 + s) * 64 + lane) * 8];
            #pragma unroll
            for (int rt = 0; rt < 4; ++rt)
                acc[rt][ct] = __builtin_amdgcn_mfma_f32_16x16x32_bf16(fa[rt], fw, acc[rt][ct], 0, 0, 0);
        }
    }

    // epilogue: C/D layout col = lane&15, row = (lane>>4)*4 + reg   [m89]
    #pragma unroll
    for (int rt = 0; rt < 4; ++rt) {
        #pragma unroll
        for (int r = 0; r < 4; ++r) {
            int row = rowBase + rt * 16 + kq * 4 + r;
            if (row < M) {
                #pragma unroll
                for (int ct = 0; ct < NT; ++ct) {
                    int col = ct * 16 + m0;
                    float v = acc[rt][ct][r] * sS[col] + sT[col];
                    if (RELU) v = fmaxf(v, 0.0f);
                    size_t o = (size_t)row * NC + col;
                    if constexpr (OUTF32) ((float*)outp)[o]  = v;
                    else                  ((__bf16*)outp)[o] = (__bf16)v;
                }
            }
        }
    }
}

extern "C" void kernel_launch(void* const* d_in, const int* in_sizes, int n_in,
                              void* d_out, int out_size, void* d_ws, size_t ws_size,
                              hipStream_t stream) {
    // inputs in setup_inputs() dict order — all floats are float32 per the harness rule
    const int*   edge_index = (const int*)d_in[0];     // [2, E_LINE]
    const float* x_orig     = (const float*)d_in[1];   // [N_NODES, 128] f32
    const int*   eio        = (const int*)d_in[2];     // [2, E_ORIG]
    const int*   pairs      = (const int*)d_in[3];     // [E_ORIG, 2]
    const float* iW1 = (const float*)d_in[4];
    const float* ib1 = (const float*)d_in[5];
    const float* ig  = (const float*)d_in[6];
    const float* ibb = (const float*)d_in[7];
    const float* im  = (const float*)d_in[8];
    const float* iv  = (const float*)d_in[9];
    const float* iW2 = (const float*)d_in[10];
    const float* ib2 = (const float*)d_in[11];
    const float* gW1 = (const float*)d_in[12];
    const float* gb1 = (const float*)d_in[13];
    const float* gg  = (const float*)d_in[14];
    const float* gbb = (const float*)d_in[15];
    const float* gm  = (const float*)d_in[16];
    const float* gv  = (const float*)d_in[17];
    const float* gW2 = (const float*)d_in[18];
    const float* gb2 = (const float*)d_in[19];
    const float* mW1 = (const float*)d_in[20];
    const float* mb1 = (const float*)d_in[21];
    const float* mg  = (const float*)d_in[22];
    const float* mbb = (const float*)d_in[23];
    const float* mm  = (const float*)d_in[24];
    const float* mv  = (const float*)d_in[25];
    const float* mW2 = (const float*)d_in[26];
    const float* mb2 = (const float*)d_in[27];
    const float* oW  = (const float*)d_in[28];
    const float* ob  = (const float*)d_in[29];

    // scratch: ONE f32 edge-sized buffer AGG (307.2 MB). Node-stage f32
    // buffers NA/NB alias its front (dead before the edge stage reuses it).
    // Edge activations E0 (bf16, 153.6 MB) live in d_out itself — the final
    // NC=64 GEMM rewrites the same 256B/row span in-place (f32 out).
    float* AGG = (float*)d_ws;                 // [E_ORIG * 128] f32
    float* NA  = AGG;                          // [N_NODES * 128] f32
    float* NB  = AGG + (size_t)N_NODES * 128;  // [N_NODES * 128] f32
    __bf16* E0 = (__bf16*)d_out;               // [E_ORIG * 128] bf16
    const size_t nodeBytes = (size_t)N_NODES * 128 * sizeof(float);

    const int* eio_src = eio;
    const int* eio_dst = eio + E_ORIG;
    const int* el_src  = edge_index;
    const int* el_dst  = edge_index + E_LINE;

    const int nGemmBlk = cdiv(N_NODES, 256);   // 391
    const int eGemmBlk = cdiv(E_ORIG, 256);    // 2344
    const int nScatBlk = E_ORIG * 32 / 256;    // 75000
    const int eScatBlk = E_LINE * 32 / 256;    // 150000
    const int cvtBlk   = E_ORIG * 128 / 8 / 256; // 37500
    const int pgBlk    = E_ORIG * 16 / 256;    // 37500

    // ---- init GIN layer 0: Q=NA ----
    hipMemcpyAsync(NA, x_orig, nodeBytes, hipMemcpyDeviceToDevice, stream);
    k_scatter_f32<<<nScatBlk, 256, 0, stream>>>(x_orig, NA, eio_src, eio_dst, E_ORIG);
    k_gemm<128, true, true,  true,  true><<<nGemmBlk, 256, 0, stream>>>(NA, N_NODES, iW1,         ib1,       ig,       ibb,       im,       iv,       NB);
    k_gemm<128, true, false, true,  true><<<nGemmBlk, 256, 0, stream>>>(NB, N_NODES, iW2,         ib2,       nullptr,  nullptr,  nullptr,  nullptr,  NA);

    // ---- init GIN layer 1: Q=NB ----
    hipMemcpyAsync(NB, NA, nodeBytes, hipMemcpyDeviceToDevice, stream);
    k_scatter_f32<<<nScatBlk, 256, 0, stream>>>(NA, NB, eio_src, eio_dst, E_ORIG);
    k_gemm<128, true, true,  true,  true><<<nGemmBlk, 256, 0, stream>>>(NB, N_NODES, iW1 + 16384, ib1 + 128, ig + 128, ibb + 128, im + 128, iv + 128, NA);
    k_gemm<128, true, false, true,  true><<<nGemmBlk, 256, 0, stream>>>(NA, N_NODES, iW2 + 16384, ib2 + 128, nullptr,  nullptr,  nullptr,  nullptr,  NB);

    // ---- per-node MLP: Y = mlp(x) (factored out of the per-edge endpoint sum) ----
    k_gemm<128, true, true,  true,  true><<<nGemmBlk, 256, 0, stream>>>(NB, N_NODES, mW1, mb1, mg, mbb, mm, mv, NA);
    k_gemm<128, true, false, false, true><<<nGemmBlk, 256, 0, stream>>>(NA, N_NODES, mW2, mb2, nullptr, nullptr, nullptr, nullptr, NB);

    // ---- h[e] = Y[p0] + Y[p1] -> E0 (bf16, in d_out) ----
    k_pair_gather<<<pgBlk, 256, 0, stream>>>(NB, pairs, E0, E_ORIG);

    // ---- line-graph GIN layer 0 ----
    k_b2f<<<cvtBlk, 256, 0, stream>>>(E0, AGG, E_ORIG * 128 / 8);       // AGG = h (overwrites NA/NB: dead)
    k_scatter_b16<<<eScatBlk, 256, 0, stream>>>(E0, AGG, el_src, el_dst, E_LINE);
    k_gemm<128, true,  true,  true, false><<<eGemmBlk, 256, 0, stream>>>(AGG, E_ORIG, gW1,         gb1,       gg,       gbb,       gm,       gv,       E0);
    k_gemm<128, false, false, true, false><<<eGemmBlk, 256, 0, stream>>>(E0,  E_ORIG, gW2,         gb2,       nullptr,  nullptr,  nullptr,  nullptr,  E0);

    // ---- line-graph GIN layer 1 ----
    k_b2f<<<cvtBlk, 256, 0, stream>>>(E0, AGG, E_ORIG * 128 / 8);
    k_scatter_b16<<<eScatBlk, 256, 0, stream>>>(E0, AGG, el_src, el_dst, E_LINE);
    k_gemm<128, true,  true,  true, false><<<eGemmBlk, 256, 0, stream>>>(AGG, E_ORIG, gW1 + 16384, gb1 + 128, gg + 128, gbb + 128, gm + 128, gv + 128, E0);
    k_gemm<128, false, false, true, false><<<eGemmBlk, 256, 0, stream>>>(E0,  E_ORIG, gW2 + 16384, gb2 + 128, nullptr,  nullptr,  nullptr,  nullptr,  E0);

    // ---- output projection: [E_ORIG,128]bf16 @ [128,64] + b -> d_out f32 (in-place span) ----
    k_gemm<64, false, false, false, true><<<eGemmBlk, 256, 0, stream>>>(E0, E_ORIG, oW, ob, nullptr, nullptr, nullptr, nullptr, d_out);
}

// Round 3
// 1409.587 us; speedup vs baseline: 5.0784x; 5.0784x over previous
//
#include <hip/hip_runtime.h>
#include <hip/hip_bf16.h>

typedef __bf16 bf8_t __attribute__((ext_vector_type(8)));
typedef float  f32x4 __attribute__((ext_vector_type(4)));

constexpr int N_NODES = 100000;
constexpr int E_ORIG  = 600000;
constexpr int E_LINE  = 1200000;

static inline int cdiv(int a, int b) { return (a + b - 1) / b; }

// ---- f32 -> bf16 pack (x_orig once) ----
__global__ void k_f2b(const float* __restrict__ X, __bf16* __restrict__ O, int n8) {
    int i = blockIdx.x * 256 + threadIdx.x;
    if (i >= n8) return;
    float4 a = ((const float4*)X)[2 * i], b = ((const float4*)X)[2 * i + 1];
    bf8_t o;
    o[0] = (__bf16)a.x; o[1] = (__bf16)a.y; o[2] = (__bf16)a.z; o[3] = (__bf16)a.w;
    o[4] = (__bf16)b.x; o[5] = (__bf16)b.y; o[6] = (__bf16)b.z; o[7] = (__bf16)b.w;
    ((bf8_t*)O)[i] = o;
}

// ---- CSR build: histogram ----
__global__ void k_hist(const int* __restrict__ dst, int* __restrict__ cnt, int E) {
    int e = blockIdx.x * 256 + threadIdx.x;
    if (e < E) atomicAdd(&cnt[dst[e]], 1);
}

// ---- CSR build: 3-phase exclusive scan over cnt[n] ----
__global__ void k_scan1(const int* __restrict__ cnt, int* __restrict__ offs,
                        int* __restrict__ bsum, int n) {
    __shared__ int tmp[256];
    int i = blockIdx.x * 256 + threadIdx.x;
    int v = (i < n) ? cnt[i] : 0;
    tmp[threadIdx.x] = v; __syncthreads();
    #pragma unroll
    for (int d = 1; d < 256; d <<= 1) {
        int t = (threadIdx.x >= d) ? tmp[threadIdx.x - d] : 0;
        __syncthreads();
        tmp[threadIdx.x] += t;
        __syncthreads();
    }
    if (i < n) offs[i] = tmp[threadIdx.x] - v;      // exclusive within block
    if (threadIdx.x == 255) bsum[blockIdx.x] = tmp[255];
}

__global__ void k_scan2(int* __restrict__ bsum, int nb) {
    __shared__ int tmp[256];
    __shared__ int carry;
    if (threadIdx.x == 0) carry = 0;
    __syncthreads();
    for (int base = 0; base < nb; base += 256) {
        int i = base + threadIdx.x;
        int v = (i < nb) ? bsum[i] : 0;
        tmp[threadIdx.x] = v; __syncthreads();
        #pragma unroll
        for (int d = 1; d < 256; d <<= 1) {
            int t = (threadIdx.x >= d) ? tmp[threadIdx.x - d] : 0;
            __syncthreads();
            tmp[threadIdx.x] += t;
            __syncthreads();
        }
        int tot = tmp[255];
        if (i < nb) bsum[i] = tmp[threadIdx.x] - v + carry;
        __syncthreads();
        if (threadIdx.x == 0) carry += tot;
        __syncthreads();
    }
}

__global__ void k_scan3(int* __restrict__ offs, int* __restrict__ cur,
                        const int* __restrict__ bsum, int n) {
    int i = blockIdx.x * 256 + threadIdx.x;
    if (i >= n) return;
    int o = offs[i] + bsum[blockIdx.x];
    offs[i] = o;
    cur[i]  = o;
}

// ---- CSR build: bucket fill ----
__global__ void k_fill(const int* __restrict__ src, const int* __restrict__ dst,
                       int* __restrict__ cur, int* __restrict__ adj, int E) {
    int e = blockIdx.x * 256 + threadIdx.x;
    if (e >= E) return;
    int p = atomicAdd(&cur[dst[e]], 1);
    adj[p] = src[e];
}

// ---- gather-aggregate: O[d] = X[d] + sum_{j in adj[offs[d]..+cnt[d])} X[j] ----
// quarter-wave (16 lanes x 16B) per row, 16 rows per 256-thread block
__global__ void k_agg(const __bf16* __restrict__ X, __bf16* __restrict__ O,
                      const int* __restrict__ offs, const int* __restrict__ cnt,
                      const int* __restrict__ adj, int nrows) {
    int row = blockIdx.x * 16 + (threadIdx.x >> 4);
    if (row >= nrows) return;
    int c = threadIdx.x & 15;
    bf8_t self = *((const bf8_t*)(X + (size_t)row * 128) + c);
    float acc[8];
    #pragma unroll
    for (int j = 0; j < 8; ++j) acc[j] = (float)self[j];
    int s = offs[row], n = cnt[row];
    for (int k = 0; k < n; ++k) {
        int nb = adj[s + k];
        bf8_t v = *((const bf8_t*)(X + (size_t)nb * 128) + c);
        #pragma unroll
        for (int j = 0; j < 8; ++j) acc[j] += (float)v[j];
    }
    bf8_t o;
    #pragma unroll
    for (int j = 0; j < 8; ++j) o[j] = (__bf16)acc[j];
    *((bf8_t*)(O + (size_t)row * 128) + c) = o;
}

// ---- h[e] = Y[p0[e]] + Y[p1[e]]  (bf16 in, f32 add, bf16 out) ----
__global__ void k_pair_gather(const __bf16* __restrict__ Y, const int* __restrict__ pairs,
                              __bf16* __restrict__ H, int E) {
    int gid = blockIdx.x * 256 + threadIdx.x;
    int e = gid >> 4;
    if (e >= E) return;
    int c = gid & 15;
    int p0 = pairs[2 * e], p1 = pairs[2 * e + 1];
    bf8_t a = *((const bf8_t*)(Y + (size_t)p0 * 128) + c);
    bf8_t b = *((const bf8_t*)(Y + (size_t)p1 * 128) + c);
    bf8_t o;
    #pragma unroll
    for (int j = 0; j < 8; ++j) o[j] = (__bf16)((float)a[j] + (float)b[j]);
    *((bf8_t*)(H + (size_t)e * 128) + c) = o;
}

// ---- fused GEMM: out = act(bn(A @ W + b)) ; A bf16 [M,128], W f32 [128,NC] ----
template<int NC, bool BN, bool RELU, bool OUTF32>
__launch_bounds__(256, 2)
__global__ void k_gemm(const __bf16* __restrict__ A, int M,
                       const float* __restrict__ W,
                       const float* __restrict__ bias,
                       const float* __restrict__ bg, const float* __restrict__ bb,
                       const float* __restrict__ bm, const float* __restrict__ bv,
                       void* __restrict__ outp) {
    constexpr int NT = NC / 16;
    __shared__ __bf16 sW[128 * NC];
    __shared__ float sS[NC];
    __shared__ float sT[NC];

    // stage W into LDS, bf16, B-fragment-major:
    // frag(c,s): lane l, elem j  <- W[k = s*32 + (l>>4)*8 + j][n = c*16 + (l&15)]
    const float4* W4 = (const float4*)W;
    for (int e = threadIdx.x; e < 32 * NC; e += 256) {
        float4 w = W4[e];
        unsigned flat = (unsigned)e * 4;
        unsigned k = flat / NC, n = flat % NC;     // 4 consecutive n share k and c
        unsigned c = n >> 4, s = k >> 5, hi = (k >> 3) & 3, j = k & 7;
        unsigned l0 = (hi << 4) | (n & 15);
        unsigned base = ((c * 4 + s) * 64 + l0) * 8 + j;
        sW[base]      = (__bf16)w.x;
        sW[base + 8]  = (__bf16)w.y;
        sW[base + 16] = (__bf16)w.z;
        sW[base + 24] = (__bf16)w.w;
    }
    // fold BN + bias into per-column scale/shift: out = dot*S + T
    for (int n = threadIdx.x; n < NC; n += 256) {
        float b = bias[n];
        float S = 1.0f, T = b;
        if (BN) {
            float g = bg[n], be = bb[n], m = bm[n], v = bv[n];
            S = g * rsqrtf(v + 1e-5f);
            T = b * S + (be - m * S);
        }
        sS[n] = S; sT[n] = T;
    }
    __syncthreads();

    const int lane = threadIdx.x & 63;
    const int wv   = threadIdx.x >> 6;
    const int rowBase = blockIdx.x * 256 + wv * 64;
    const int m0 = lane & 15, kq = lane >> 4;

    f32x4 acc[4][NT];
    #pragma unroll
    for (int rt = 0; rt < 4; ++rt)
        #pragma unroll
        for (int ct = 0; ct < NT; ++ct)
            acc[rt][ct] = (f32x4){0.f, 0.f, 0.f, 0.f};

    #pragma unroll
    for (int s = 0; s < 4; ++s) {
        bf8_t fa[4];
        #pragma unroll
        for (int rt = 0; rt < 4; ++rt) {
            int r = rowBase + rt * 16 + m0;
            r = r < M ? r : M - 1;                 // clamp; tail rows never stored
            fa[rt] = *(const bf8_t*)(A + (size_t)r * 128 + s * 32 + kq * 8);
        }
        #pragma unroll
        for (int ct = 0; ct < NT; ++ct) {
            bf8_t fw = *(const bf8_t*)&sW[((ct * 4 + s) * 64 + lane) * 8];
            #pragma unroll
            for (int rt = 0; rt < 4; ++rt)
                acc[rt][ct] = __builtin_amdgcn_mfma_f32_16x16x32_bf16(fa[rt], fw, acc[rt][ct], 0, 0, 0);
        }
    }

    // epilogue: C/D layout col = lane&15, row = (lane>>4)*4 + reg   [m89]
    #pragma unroll
    for (int rt = 0; rt < 4; ++rt) {
        #pragma unroll
        for (int r = 0; r < 4; ++r) {
            int row = rowBase + rt * 16 + kq * 4 + r;
            if (row < M) {
                #pragma unroll
                for (int ct = 0; ct < NT; ++ct) {
                    int col = ct * 16 + m0;
                    float v = acc[rt][ct][r] * sS[col] + sT[col];
                    if (RELU) v = fmaxf(v, 0.0f);
                    size_t o = (size_t)row * NC + col;
                    if constexpr (OUTF32) ((float*)outp)[o]  = v;
                    else                  ((__bf16*)outp)[o] = (__bf16)v;
                }
            }
        }
    }
}

extern "C" void kernel_launch(void* const* d_in, const int* in_sizes, int n_in,
                              void* d_out, int out_size, void* d_ws, size_t ws_size,
                              hipStream_t stream) {
    const int*   edge_index = (const int*)d_in[0];     // [2, E_LINE]
    const float* x_orig     = (const float*)d_in[1];   // [N_NODES, 128] f32
    const int*   eio        = (const int*)d_in[2];     // [2, E_ORIG]
    const int*   pairs      = (const int*)d_in[3];     // [E_ORIG, 2]
    const float* iW1 = (const float*)d_in[4];
    const float* ib1 = (const float*)d_in[5];
    const float* ig  = (const float*)d_in[6];
    const float* ibb = (const float*)d_in[7];
    const float* im  = (const float*)d_in[8];
    const float* iv  = (const float*)d_in[9];
    const float* iW2 = (const float*)d_in[10];
    const float* ib2 = (const float*)d_in[11];
    const float* gW1 = (const float*)d_in[12];
    const float* gb1 = (const float*)d_in[13];
    const float* gg  = (const float*)d_in[14];
    const float* gbb = (const float*)d_in[15];
    const float* gm  = (const float*)d_in[16];
    const float* gv  = (const float*)d_in[17];
    const float* gW2 = (const float*)d_in[18];
    const float* gb2 = (const float*)d_in[19];
    const float* mW1 = (const float*)d_in[20];
    const float* mb1 = (const float*)d_in[21];
    const float* mg  = (const float*)d_in[22];
    const float* mbb = (const float*)d_in[23];
    const float* mm  = (const float*)d_in[24];
    const float* mv  = (const float*)d_in[25];
    const float* mW2 = (const float*)d_in[26];
    const float* mb2 = (const float*)d_in[27];
    const float* oW  = (const float*)d_in[28];
    const float* ob  = (const float*)d_in[29];

    // ---- workspace carve (all bf16 activations; ~242 MB of the proven >=307 MB) ----
    char* w = (char*)d_ws;
    __bf16* EB  = (__bf16*)w;                w += (size_t)E_ORIG * 128 * 2;   // 153.6 MB
    __bf16* XB  = (__bf16*)w;                w += (size_t)N_NODES * 128 * 2;  // 25.6 MB
    __bf16* NA  = (__bf16*)w;                w += (size_t)N_NODES * 128 * 2;  // 25.6 MB
    __bf16* NB  = (__bf16*)w;                w += (size_t)N_NODES * 128 * 2;  // 25.6 MB
    int* cnt  = (int*)w;                     w += (size_t)E_ORIG * 4;         // 2.4 MB
    int* offs = (int*)w;                     w += (size_t)E_ORIG * 4;         // 2.4 MB
    int* cur  = (int*)w;                     w += (size_t)E_ORIG * 4;         // 2.4 MB
    int* bsum = (int*)w;                     w += 4096 * 4;
    int* adj  = (int*)w;                     /* E_LINE ints, 4.8 MB */
    __bf16* E0 = (__bf16*)d_out;             // [E_ORIG*128] bf16 lives in d_out

    const int* eio_src = eio;
    const int* eio_dst = eio + E_ORIG;
    const int* el_src  = edge_index;
    const int* el_dst  = edge_index + E_LINE;

    const int nGemmBlk = cdiv(N_NODES, 256);
    const int eGemmBlk = cdiv(E_ORIG, 256);
    const int nAggBlk  = cdiv(N_NODES, 16);
    const int eAggBlk  = cdiv(E_ORIG, 16);
    const int nScanNB  = cdiv(N_NODES, 256);   // 391
    const int eScanNB  = cdiv(E_ORIG, 256);    // 2344

    // ==== node-graph CSR (dst = eio_dst, n = N_NODES, E = E_ORIG) ====
    hipMemsetAsync(cnt, 0, (size_t)N_NODES * 4, stream);
    k_hist <<<cdiv(E_ORIG, 256), 256, 0, stream>>>(eio_dst, cnt, E_ORIG);
    k_scan1<<<nScanNB, 256, 0, stream>>>(cnt, offs, bsum, N_NODES);
    k_scan2<<<1, 256, 0, stream>>>(bsum, nScanNB);
    k_scan3<<<nScanNB, 256, 0, stream>>>(offs, cur, bsum, N_NODES);
    k_fill <<<cdiv(E_ORIG, 256), 256, 0, stream>>>(eio_src, eio_dst, cur, adj, E_ORIG);

    // ==== node stage ====
    k_f2b<<<cdiv(N_NODES * 16, 256), 256, 0, stream>>>(x_orig, XB, N_NODES * 16);
    // init GIN layer 0
    k_agg<<<nAggBlk, 256, 0, stream>>>(XB, NA, offs, cnt, adj, N_NODES);
    k_gemm<128, true,  true,  false><<<nGemmBlk, 256, 0, stream>>>(NA, N_NODES, iW1,         ib1,       ig,       ibb,       im,       iv,       NB);
    k_gemm<128, false, true,  false><<<nGemmBlk, 256, 0, stream>>>(NB, N_NODES, iW2,         ib2,       nullptr,  nullptr,  nullptr,  nullptr,  XB);
    // init GIN layer 1
    k_agg<<<nAggBlk, 256, 0, stream>>>(XB, NA, offs, cnt, adj, N_NODES);
    k_gemm<128, true,  true,  false><<<nGemmBlk, 256, 0, stream>>>(NA, N_NODES, iW1 + 16384, ib1 + 128, ig + 128, ibb + 128, im + 128, iv + 128, NB);
    k_gemm<128, false, true,  false><<<nGemmBlk, 256, 0, stream>>>(NB, N_NODES, iW2 + 16384, ib2 + 128, nullptr,  nullptr,  nullptr,  nullptr,  NA);
    // per-node MLP: Y = mlp(act1)  (factored out of the per-edge endpoint sum)
    k_gemm<128, true,  true,  false><<<nGemmBlk, 256, 0, stream>>>(NA, N_NODES, mW1, mb1, mg, mbb, mm, mv, NB);
    k_gemm<128, false, false, false><<<nGemmBlk, 256, 0, stream>>>(NB, N_NODES, mW2, mb2, nullptr, nullptr, nullptr, nullptr, XB);
    // h[e] = Y[p0] + Y[p1] -> EB
    k_pair_gather<<<cdiv(E_ORIG * 16, 256), 256, 0, stream>>>(XB, pairs, EB, E_ORIG);

    // ==== line-graph CSR (dst = el_dst, n = E_ORIG, E = E_LINE) ====
    hipMemsetAsync(cnt, 0, (size_t)E_ORIG * 4, stream);
    k_hist <<<cdiv(E_LINE, 256), 256, 0, stream>>>(el_dst, cnt, E_LINE);
    k_scan1<<<eScanNB, 256, 0, stream>>>(cnt, offs, bsum, E_ORIG);
    k_scan2<<<1, 256, 0, stream>>>(bsum, eScanNB);
    k_scan3<<<eScanNB, 256, 0, stream>>>(offs, cur, bsum, E_ORIG);
    k_fill <<<cdiv(E_LINE, 256), 256, 0, stream>>>(el_src, el_dst, cur, adj, E_LINE);

    // ==== edge stage ====
    // GIN layer 0
    k_agg<<<eAggBlk, 256, 0, stream>>>(EB, E0, offs, cnt, adj, E_ORIG);
    k_gemm<128, true,  true,  false><<<eGemmBlk, 256, 0, stream>>>(E0, E_ORIG, gW1,         gb1,       gg,       gbb,       gm,       gv,       EB);
    k_gemm<128, false, true,  false><<<eGemmBlk, 256, 0, stream>>>(EB, E_ORIG, gW2,         gb2,       nullptr,  nullptr,  nullptr,  nullptr,  E0);
    // GIN layer 1
    k_agg<<<eAggBlk, 256, 0, stream>>>(E0, EB, offs, cnt, adj, E_ORIG);
    k_gemm<128, true,  true,  false><<<eGemmBlk, 256, 0, stream>>>(EB, E_ORIG, gW1 + 16384, gb1 + 128, gg + 128, gbb + 128, gm + 128, gv + 128, E0);
    k_gemm<128, false, true,  false><<<eGemmBlk, 256, 0, stream>>>(E0, E_ORIG, gW2 + 16384, gb2 + 128, nullptr,  nullptr,  nullptr,  nullptr,  EB);

    // ==== output projection: [E_ORIG,128]bf16 @ [128,64] + b -> d_out f32 ====
    k_gemm<64, false, false, true><<<eGemmBlk, 256, 0, stream>>>(EB, E_ORIG, oW, ob, nullptr, nullptr, nullptr, nullptr, d_out);
}